// Round 20
// baseline (333.364 us; speedup 1.0000x reference)
//
#include <hip/hip_runtime.h>

// ---------------------------------------------------------------------------
// Bidirectional Mamba block, MI355X. Round 19: kconv3 2-co-per-thread
// (128 thr/block). R15-R18 analysis: kconv3 was DS-pipe bound (5 DS insts per
// 48 FMA, ~48us/CU DS vs ~29us VALU). Same staging, half the threads, 2 co
// accumulators each -> DS halved, FMA/DS ratio doubled.
// Everything else identical to passing R18 (324us).
// Shapes: B=4, C=64, D=128, L=4096 (l = h*256 + w*16 + t), N=16, R=8.
// ---------------------------------------------------------------------------

#define NL 4096

typedef unsigned short u16;
typedef unsigned int u32;

__device__ __forceinline__ float siluf_(float x) { return x / (1.f + __expf(-x)); }
__device__ __forceinline__ float softplusf_(float x) {
  return (x > 20.f) ? x : log1pf(__expf(x));
}
__device__ __forceinline__ u16 f2bf(float f) {
  u32 u = __float_as_uint(f);
  u += 0x7fffu + ((u >> 16) & 1u);
  return (u16)(u >> 16);
}
__device__ __forceinline__ float bflo(u32 v) { return __uint_as_float(v << 16); }
__device__ __forceinline__ float bfhi(u32 v) { return __uint_as_float(v & 0xFFFF0000u); }

// Sum over the 16-lane DPP row via rotations 1,2,4,8 (VALU pipe, no DS).
__device__ __forceinline__ float rowsum16_(float p) {
  int q;
  q = __builtin_amdgcn_mov_dpp(__float_as_int(p), 0x121, 0xf, 0xf, false);
  p += __int_as_float(q);
  q = __builtin_amdgcn_mov_dpp(__float_as_int(p), 0x122, 0xf, 0xf, false);
  p += __int_as_float(q);
  q = __builtin_amdgcn_mov_dpp(__float_as_int(p), 0x124, 0xf, 0xf, false);
  p += __int_as_float(q);
  q = __builtin_amdgcn_mov_dpp(__float_as_int(p), 0x128, 0xf, 0xf, false);
  p += __int_as_float(q);
  return p;
}

// Per-b slab offsets (fp32 elements; bf16 regions use u16 views at same base)
#define OXZ  0u          // xz [256][4096] fp32; becomes conv3 partials q0/q1
#define OUCF 1048576u    // ucf [128][4096] bf16 (u16 view)
#define OUCB 1572864u    // ucb [128][4096] bf16 (flipped coords)
#define ODLF 2424832u    // dlf [128][4096] bf16
#define ODLB 2949120u    // dlb [128][4096] bf16 (flipped coords)
#define OYF  3473408u    // yf [128][4096] fp32; becomes conv3 partial q2 (OX4B)
#define OYB  3997696u    // yb [128][4096] fp32 (flipped coords)
#define OO   4521984u    // scan scratch: P [262144] S [262144] fp32
#define OO2  5046272u    // bct [2][4096][32] bf16 until kscanC; then o2 [4096][64] fp32
#define OX4  5308416u    // conv3 partial q3 (+bias+residual)
#define OX4B 3473408u    // conv3 partial q2 (over dead yf)
#define PER_B 5570560u

#define NCH 64   // scan chunks
#define CL  64   // chunk length

// 1. xz[e,l] = sum_c in_proj_w[e,c] * seq[c,l].
__global__ __launch_bounds__(256) void kxz(
    const float* __restrict__ x, const float* __restrict__ wip,
    float* __restrict__ ws, int b0) {
  int bi = blockIdx.y, gb = b0 + bi;
  float* s = ws + (size_t)bi * PER_B;
  int bid = blockIdx.x;
  int h = bid >> 4, w = bid & 15;
  int tid = threadIdx.x;
  __shared__ float xs[64][16];
  for (int i = tid; i < 1024; i += 256) {
    int c = i >> 4, t = i & 15;
    xs[c][t] = x[(size_t)(gb * 64 + c) * NL + t * 256 + h * 16 + w];
  }
  __syncthreads();
  int e = tid;
  float acc[16];
#pragma unroll
  for (int t = 0; t < 16; ++t) acc[t] = 0.f;
  for (int c = 0; c < 64; ++c) {
    float wv = wip[e * 64 + c];
#pragma unroll
    for (int t = 0; t < 16; ++t) acc[t] = fmaf(wv, xs[c][t], acc[t]);
  }
  float4* dst = (float4*)(s + OXZ + (size_t)e * NL + h * 256 + w * 16);
#pragma unroll
  for (int q = 0; q < 4; ++q)
    dst[q] = make_float4(acc[q * 4], acc[q * 4 + 1], acc[q * 4 + 2], acc[q * 4 + 3]);
}

// 2. Fused prep per (bi, 32-l tile): dwconv+silu, x_dbl (float4), delta, bct.
// uc/dl/bct stored bf16 (fp32 compute in LDS).
__global__ __launch_bounds__(256) void k2prep(
    const float* __restrict__ cwf, const float* __restrict__ cbf,
    const float* __restrict__ xpf, const float* __restrict__ dtwf,
    const float* __restrict__ dtbf,
    const float* __restrict__ cwb, const float* __restrict__ cbb,
    const float* __restrict__ xpb, const float* __restrict__ dtwb,
    const float* __restrict__ dtbb,
    float* __restrict__ ws) {
  int bi = blockIdx.y;
  float* s = ws + (size_t)bi * PER_B;
  int lt = blockIdx.x;
  int l0 = lt * 32;
  int l0b = (127 - lt) * 32;
  int tid = threadIdx.x;

  __shared__ float pool[128 * 40];   // X[128][40] during dwconv; xds after
  __shared__ float ucs[2][128][32];
  float (*X)[40] = (float(*)[40])pool;

  for (int i = tid; i < 128 * 38; i += 256) {
    int d = i / 38, j = i - d * 38;
    int l = l0 - 3 + j;
    X[d][j] = (l >= 0 && l < NL) ? s[OXZ + (size_t)d * NL + l] : 0.f;
  }
  __syncthreads();

  u16* ucfp = (u16*)(s + OUCF);
  u16* ucbp = (u16*)(s + OUCB);
  for (int i = tid; i < 2 * 128 * 32; i += 256) {
    int br = i >> 12, rem = i & 4095;
    int d = rem >> 5, li = rem & 31;
    float a;
    if (br == 0) {
      a = cbf[d];
#pragma unroll
      for (int k = 0; k < 4; ++k) a = fmaf(cwf[d * 4 + k], X[d][li + k], a);
    } else {
      a = cbb[d];
#pragma unroll
      for (int k = 0; k < 4; ++k) a = fmaf(cwb[d * 4 + k], X[d][37 - li - k], a);
    }
    a = siluf_(a);
    ucs[br][d][li] = a;
    int lg = br ? (l0b + li) : (l0 + li);
    (br ? ucbp : ucfp)[(size_t)d * NL + lg] = f2bf(a);
  }
  __syncthreads();  // X dead; pool becomes xds [2][40][33]

  float* xds = pool;
  for (int i = tid; i < 640; i += 256) {
    int br = i / 320;
    int rem = i - br * 320;
    int e = rem >> 3, liq = rem & 7;
    const float* xp = br ? xpb : xpf;
    float4 acc = make_float4(0.f, 0.f, 0.f, 0.f);
    for (int d = 0; d < 128; ++d) {
      float wv = xp[e * 128 + d];
      const float4 u4 = *(const float4*)&ucs[br][d][liq * 4];
      acc.x = fmaf(wv, u4.x, acc.x);
      acc.y = fmaf(wv, u4.y, acc.y);
      acc.z = fmaf(wv, u4.z, acc.z);
      acc.w = fmaf(wv, u4.w, acc.w);
    }
    float* dst = &xds[(br * 40 + e) * 33 + liq * 4];
    dst[0] = acc.x; dst[1] = acc.y; dst[2] = acc.z; dst[3] = acc.w;
  }
  __syncthreads();

  u16* dlfp = (u16*)(s + ODLF);
  u16* dlbp = (u16*)(s + ODLB);
  for (int i = tid; i < 2 * 128 * 32; i += 256) {
    int br = i >> 12, rem = i & 4095;
    int d = rem >> 5, li = rem & 31;
    const float* dtw = br ? dtwb : dtwf;
    float pre = (br ? dtbb : dtbf)[d];
#pragma unroll
    for (int r = 0; r < 8; ++r)
      pre = fmaf(dtw[d * 8 + r], xds[(br * 40 + r) * 33 + li], pre);
    int lg = br ? (l0b + li) : (l0 + li);
    (br ? dlbp : dlfp)[(size_t)d * NL + lg] = f2bf(softplusf_(pre));
  }
  u16* bctp = (u16*)(s + OO2);
  for (int i = tid; i < 2 * 32 * 32; i += 256) {
    int dir = i >> 10;
    int li = (i >> 5) & 31, k = i & 31;
    int lg = dir ? (l0b + li) : (l0 + li);
    bctp[((size_t)dir * 4096 + lg) * 32 + k] = f2bf(xds[(dir * 40 + 8 + k) * 33 + li]);
  }
}

// 5a. Phase A: 16 d-rows/block; chunk bct (bf16) staged to fp32 LDS;
// ushort8 dl/uc loads = 8 steps per load pair.
__global__ __launch_bounds__(256) void kscanA(
    const float* __restrict__ Alf, const float* __restrict__ Alb,
    float* __restrict__ ws) {
  int bi = blockIdx.y;
  float* s = ws + (size_t)bi * PER_B;
  int xid = blockIdx.x;
  int chunk = xid >> 4, dir = (xid >> 3) & 1, d8 = xid & 7;
  int tid = threadIdx.x;
  int wv = tid >> 6, lane = tid & 63;
  int n = lane & 15, g = lane >> 4;
  int d = d8 * 16 + wv * 4 + g;
  int l0 = chunk * CL;
  __shared__ float bl[CL * 32];
  {
    const u16* bctp = (const u16*)(s + OO2) + ((size_t)dir * 4096 + l0) * 32;
    for (int i = tid; i < CL * 32; i += 256)
      bl[i] = __uint_as_float(((u32)bctp[i]) << 16);
  }
  __syncthreads();
  const u16* ucp = (const u16*)(s + (dir ? OUCB : OUCF)) + (size_t)d * NL + l0;
  const u16* dlp = (const u16*)(s + (dir ? ODLB : ODLF)) + (size_t)d * NL + l0;
  float A = -__expf((dir ? Alb : Alf)[d * 16 + n]);
  float P = 1.f, S = 0.f;
  for (int i0 = 0; i0 < CL; i0 += 8) {
    uint4 dq = *(const uint4*)(dlp + i0);
    uint4 uq = *(const uint4*)(ucp + i0);
    float dv[8] = {bflo(dq.x), bfhi(dq.x), bflo(dq.y), bfhi(dq.y),
                   bflo(dq.z), bfhi(dq.z), bflo(dq.w), bfhi(dq.w)};
    float uv[8] = {bflo(uq.x), bfhi(uq.x), bflo(uq.y), bfhi(uq.y),
                   bflo(uq.z), bfhi(uq.z), bflo(uq.w), bfhi(uq.w)};
#pragma unroll
    for (int j = 0; j < 8; ++j) {
      float dA = __expf(dv[j] * A);
      S = fmaf(dA, S, dv[j] * bl[(i0 + j) * 32 + n] * uv[j]);
      P *= dA;
    }
  }
  size_t cidx = ((size_t)(chunk * 2 + dir) * 128 + d) * 16 + n;
  s[OO + cidx] = P;
  s[OO + 262144u + cidx] = S;
}

// 5b. Phase B: carry combine.
__global__ __launch_bounds__(64) void kscanB(float* __restrict__ ws) {
  int bi = blockIdx.y;
  float* s = ws + (size_t)bi * PER_B;
  int dir = blockIdx.x >> 5, dblk = blockIdx.x & 31;
  int tid = threadIdx.x;
  size_t base = (size_t)dir * 2048 + dblk * 64 + tid;
  float carry = 0.f;
#pragma unroll 4
  for (int c = 0; c < NCH; ++c) {
    size_t idx = (size_t)c * 4096 + base;
    float pv = s[OO + idx], sv = s[OO + 262144u + idx];
    s[OO + 262144u + idx] = carry;
    carry = fmaf(pv, carry, sv);
  }
}

// 5c. Phase C: seeded re-scan; bf16 inputs; DPP row-sum; ps[16][65] staging.
__global__ __launch_bounds__(256) void kscanC(
    const float* __restrict__ Alf, const float* __restrict__ Df,
    const float* __restrict__ Alb, const float* __restrict__ Db,
    float* __restrict__ ws) {
  int bi = blockIdx.y;
  float* s = ws + (size_t)bi * PER_B;
  int xid = blockIdx.x;
  int chunk = xid >> 4, dir = (xid >> 3) & 1, d8 = xid & 7;
  int tid = threadIdx.x;
  int wv = tid >> 6, lane = tid & 63;
  int n = lane & 15, g = lane >> 4;
  int d = d8 * 16 + wv * 4 + g;
  int l0 = chunk * CL;
  __shared__ float bl[CL * 32];
  __shared__ float ps[16][65];
  {
    const u16* bctp = (const u16*)(s + OO2) + ((size_t)dir * 4096 + l0) * 32;
    for (int i = tid; i < CL * 32; i += 256)
      bl[i] = __uint_as_float(((u32)bctp[i]) << 16);
  }
  __syncthreads();
  const u16* ucp = (const u16*)(s + (dir ? OUCB : OUCF)) + (size_t)d * NL + l0;
  const u16* dlp = (const u16*)(s + (dir ? ODLB : ODLF)) + (size_t)d * NL + l0;
  float* ybase = s + (dir ? OYB : OYF);
  float A = -__expf((dir ? Alb : Alf)[d * 16 + n]);
  float Dv = (dir ? Db : Df)[d];
  size_t cidx = ((size_t)(chunk * 2 + dir) * 128 + d) * 16 + n;
  float h = s[OO + 262144u + cidx];
  int prow = wv * 4 + g;
  for (int i0 = 0; i0 < CL; i0 += 8) {
    uint4 dq = *(const uint4*)(dlp + i0);
    uint4 uq = *(const uint4*)(ucp + i0);
    float dv[8] = {bflo(dq.x), bfhi(dq.x), bflo(dq.y), bfhi(dq.y),
                   bflo(dq.z), bfhi(dq.z), bflo(dq.w), bfhi(dq.w)};
    float uv[8] = {bflo(uq.x), bfhi(uq.x), bflo(uq.y), bfhi(uq.y),
                   bflo(uq.z), bfhi(uq.z), bflo(uq.w), bfhi(uq.w)};
#pragma unroll
    for (int j = 0; j < 8; ++j) {
      int i = i0 + j;
      float dA = __expf(dv[j] * A);
      h = fmaf(dA, h, dv[j] * bl[i * 32 + n] * uv[j]);
      float p = rowsum16_(h * bl[i * 32 + 16 + n]);
      if (n == 0) ps[prow][i] = fmaf(uv[j], Dv, p);
    }
  }
  __syncthreads();
  for (int i = tid; i < 16 * CL; i += 256) {
    int row = i >> 6, col = i & 63;
    ybase[(size_t)(d8 * 16 + row) * NL + l0 + col] = ps[row][col];
  }
}

// 6. Fused gate + out-proj. Block = 32-l tile.
__global__ __launch_bounds__(256) void koutg(
    const float* __restrict__ wout, float* __restrict__ ws) {
  int bi = blockIdx.y;
  float* s = ws + (size_t)bi * PER_B;
  int lt = blockIdx.x;
  int l0 = lt * 32;
  int tid = threadIdx.x;
  __shared__ float ot[128][32];
  __shared__ float ot2[64][33];
  for (int i = tid; i < 128 * 32; i += 256) {
    int d = i >> 5, li = i & 31;
    int l = l0 + li;
    float z = s[OXZ + (size_t)(128 + d) * NL + l];
    float v = s[OYF + (size_t)d * NL + l] + s[OYB + (size_t)d * NL + (NL - 1 - l)];
    ot[d][li] = v * siluf_(z);
  }
  __syncthreads();
  {
    int li = tid & 31, cg = tid >> 5;
    float acc[8];
#pragma unroll
    for (int j = 0; j < 8; ++j) acc[j] = 0.f;
    for (int d = 0; d < 128; ++d) {
      float xv = ot[d][li];
#pragma unroll
      for (int j = 0; j < 8; ++j)
        acc[j] = fmaf(wout[(cg * 8 + j) * 128 + d], xv, acc[j]);
    }
#pragma unroll
    for (int j = 0; j < 8; ++j) ot2[cg * 8 + j][li] = acc[j];
  }
  __syncthreads();
  for (int i = tid; i < 32 * 64; i += 256) {
    int li = i >> 6, c = i & 63;
    s[OO2 + (size_t)(l0 + li) * 64 + c] = ot2[c][li];
  }
}

// 7. conv3d partials. Grid = (t, hq, ciq<4): 256 blocks/slab (4/CU).
// 128 threads = 32 co-slots x 4 hh; each thread computes co AND co+32
// (96 FMA per 5 DS insts -> DS pipe load halved vs R18).
__global__ __launch_bounds__(128) void kconv3(
    const float* __restrict__ pw, const float* __restrict__ pb,
    const float* __restrict__ xin, float* __restrict__ ws, int b0) {
  int bi = blockIdx.y, gb = b0 + bi;
  float* s = ws + (size_t)bi * PER_B;
  int t = blockIdx.x >> 4, hq = (blockIdx.x >> 2) & 3, ciq = blockIdx.x & 3;
  int h0 = hq * 4;
  int tid = threadIdx.x;       // 0..127
  int co = tid >> 2, hh = tid & 3;  // co 0..31; second co = co+32
  int h = h0 + hh;
  const float* xr = s + OO2;
  __shared__ float Xs[16][3][6][20];
  float acc0[16], acc1[16];
#pragma unroll
  for (int w = 0; w < 16; ++w) { acc0[w] = 0.f; acc1[w] = 0.f; }

  for (int i = tid; i < 16 * 360; i += 128) {
    int ci = i / 360;
    int rem = i - ci * 360;
    int tt = rem / 120;
    int rem2 = rem - tt * 120;
    int hh2 = rem2 / 20;
    int ww = rem2 - hh2 * 20;
    int ts = t + tt - 1, hs = h0 + hh2 - 1, wvv = ww - 1;
    float v = 0.f;
    if (ts >= 0 && ts < 16 && hs >= 0 && hs < 16 && wvv >= 0 && wvv < 16)
      v = xr[(size_t)(ciq * 16 + ci) * NL + ts * 256 + hs * 16 + wvv];
    Xs[ci][tt][hh2][ww] = v;
  }
  __syncthreads();
  const float* wc0 = pw + (co * 64 + ciq * 16) * 27;
  const float* wc1 = pw + ((co + 32) * 64 + ciq * 16) * 27;
  for (int ci = 0; ci < 16; ++ci) {
#pragma unroll
    for (int kt = 0; kt < 3; ++kt) {
#pragma unroll
      for (int kh = 0; kh < 3; ++kh) {
        int woff = ci * 27 + kt * 9 + kh * 3;
        const float* wr0 = wc0 + woff;
        const float* wr1 = wc1 + woff;
        float a0 = wr0[0], a1 = wr0[1], a2 = wr0[2];
        float b0_ = wr1[0], b1_ = wr1[1], b2_ = wr1[2];
        const float* row = &Xs[ci][kt][hh + kh][0];
        float4 r0 = *(const float4*)&row[0];
        float4 r1 = *(const float4*)&row[4];
        float4 r2 = *(const float4*)&row[8];
        float4 r3 = *(const float4*)&row[12];
        float2 r4 = *(const float2*)&row[16];
        float xv[18] = {r0.x, r0.y, r0.z, r0.w, r1.x, r1.y, r1.z, r1.w,
                        r2.x, r2.y, r2.z, r2.w, r3.x, r3.y, r3.z, r3.w,
                        r4.x, r4.y};
#pragma unroll
        for (int w = 0; w < 16; ++w) {
          acc0[w] = fmaf(a0, xv[w], fmaf(a1, xv[w + 1], fmaf(a2, xv[w + 2], acc0[w])));
          acc1[w] = fmaf(b0_, xv[w], fmaf(b1_, xv[w + 1], fmaf(b2_, xv[w + 2], acc1[w])));
        }
      }
    }
  }
  size_t off0 = (size_t)co * NL + t * 256 + h * 16;
  size_t off1 = (size_t)(co + 32) * NL + t * 256 + h * 16;
  if (ciq == 3) {
    float bias0 = pb[co], bias1 = pb[co + 32];
    size_t ib0 = (size_t)(gb * 64 + co) * NL + t * 256 + h * 16;
    size_t ib1 = (size_t)(gb * 64 + co + 32) * NL + t * 256 + h * 16;
#pragma unroll
    for (int w = 0; w < 16; ++w) {
      s[OX4 + off0 + w] = acc0[w] + bias0 + xin[ib0 + w];
      s[OX4 + off1 + w] = acc1[w] + bias1 + xin[ib1 + w];
    }
  } else {
    size_t dsto = (ciq == 2) ? OX4B : (ciq == 1 ? (OXZ + 262144u) : OXZ);
#pragma unroll
    for (int w = 0; w < 16; ++w) {
      s[dsto + off0 + w] = acc0[w];
      s[dsto + off1 + w] = acc1[w];
    }
  }
}

// 8. knorm: LDS-tiled 1x1x1 mix over the 4-partial sum + norm_b.
__global__ __launch_bounds__(256) void knorm(
    const float* __restrict__ nw, const float* __restrict__ nb,
    float* __restrict__ out, float* __restrict__ ws, int b0) {
  int bi = blockIdx.y, gb = b0 + bi;
  float* s = ws + (size_t)bi * PER_B;
  int pt = blockIdx.x;
  int p0 = pt * 64;
  int tid = threadIdx.x;
  __shared__ float xs[64][64];
  for (int i = tid; i < 4096; i += 256) {
    int ci = i >> 6, p = i & 63;
    size_t o = (size_t)ci * NL + p0 + p;
    xs[ci][p] = s[OX4 + o] + s[OX4B + o] + s[OXZ + o] + s[OXZ + 262144u + o];
  }
  __syncthreads();
  int co = tid >> 2, pq = tid & 3;
  float acc[16];
#pragma unroll
  for (int j = 0; j < 16; ++j) acc[j] = 0.f;
  for (int ci = 0; ci < 64; ++ci) {
    float wv = nw[co * 64 + ci];
    const float4* row = (const float4*)&xs[ci][pq * 16];
    float4 a = row[0], b = row[1], c = row[2], e = row[3];
    acc[0] = fmaf(wv, a.x, acc[0]);  acc[1] = fmaf(wv, a.y, acc[1]);
    acc[2] = fmaf(wv, a.z, acc[2]);  acc[3] = fmaf(wv, a.w, acc[3]);
    acc[4] = fmaf(wv, b.x, acc[4]);  acc[5] = fmaf(wv, b.y, acc[5]);
    acc[6] = fmaf(wv, b.z, acc[6]);  acc[7] = fmaf(wv, b.w, acc[7]);
    acc[8] = fmaf(wv, c.x, acc[8]);  acc[9] = fmaf(wv, c.y, acc[9]);
    acc[10] = fmaf(wv, c.z, acc[10]); acc[11] = fmaf(wv, c.w, acc[11]);
    acc[12] = fmaf(wv, e.x, acc[12]); acc[13] = fmaf(wv, e.y, acc[13]);
    acc[14] = fmaf(wv, e.z, acc[14]); acc[15] = fmaf(wv, e.w, acc[15]);
  }
  float bias = nb[co];
  float4* dst = (float4*)(out + (size_t)(gb * 64 + co) * NL + p0 + pq * 16);
#pragma unroll
  for (int q = 0; q < 4; ++q)
    dst[q] = make_float4(acc[q * 4] + bias, acc[q * 4 + 1] + bias,
                         acc[q * 4 + 2] + bias, acc[q * 4 + 3] + bias);
}

// ---------------------------------------------------------------------------
extern "C" void kernel_launch(void* const* d_in, const int* in_sizes, int n_in,
                              void* d_out, int out_size, void* d_ws, size_t ws_size,
                              hipStream_t stream) {
  const float* x    = (const float*)d_in[0];
  const float* wip  = (const float*)d_in[1];
  const float* cwf  = (const float*)d_in[2];
  const float* cbf  = (const float*)d_in[3];
  const float* xpf  = (const float*)d_in[4];
  const float* dtwf = (const float*)d_in[5];
  const float* dtbf = (const float*)d_in[6];
  const float* Alf  = (const float*)d_in[7];
  const float* Df   = (const float*)d_in[8];
  const float* cwb  = (const float*)d_in[9];
  const float* cbb  = (const float*)d_in[10];
  const float* xpb  = (const float*)d_in[11];
  const float* dtwb = (const float*)d_in[12];
  const float* dtbb = (const float*)d_in[13];
  const float* Alb  = (const float*)d_in[14];
  const float* Db   = (const float*)d_in[15];
  const float* wout = (const float*)d_in[16];
  const float* pw   = (const float*)d_in[17];
  const float* pb   = (const float*)d_in[18];
  const float* nw   = (const float*)d_in[19];
  const float* nb   = (const float*)d_in[20];

  const size_t PER_B_BYTES = (size_t)PER_B * 4;  // 22,282,240 per batch slab
  int bcnt;
  if (ws_size >= 4 * PER_B_BYTES) bcnt = 4;
  else if (ws_size >= PER_B_BYTES) bcnt = 1;
  else return;
  int passes = 4 / bcnt;

  float* ws = (float*)d_ws;
  for (int p = 0; p < passes; ++p) {
    int b0 = p * bcnt;
    kxz   <<<dim3(256, bcnt), 256, 0, stream>>>(x, wip, ws, b0);
    k2prep<<<dim3(128, bcnt), 256, 0, stream>>>(cwf, cbf, xpf, dtwf, dtbf,
                                                cwb, cbb, xpb, dtwb, dtbb, ws);
    kscanA<<<dim3(1024, bcnt), 256, 0, stream>>>(Alf, Alb, ws);
    kscanB<<<dim3(64, bcnt), 64, 0, stream>>>(ws);
    kscanC<<<dim3(1024, bcnt), 256, 0, stream>>>(Alf, Df, Alb, Db, ws);
    koutg <<<dim3(128, bcnt), 256, 0, stream>>>(wout, ws);
    kconv3<<<dim3(256, bcnt), 128, 0, stream>>>(pw, pb, x, ws, b0);
    knorm <<<dim3(64, bcnt), 256, 0, stream>>>(nw, nb, (float*)d_out, ws, b0);
  }
}

// Round 21
// 323.529 us; speedup vs baseline: 1.0304x; 1.0304x over previous
//
#include <hip/hip_runtime.h>

// ---------------------------------------------------------------------------
// Bidirectional Mamba block, MI355X. Round 20:
//  - kconv3 reverted to R18 form (best known, ~68us; R16/R17/R19 theories all
//    falsified -> declared at practical fp32 bound)
//  - koutg: d-step-4 with float4 weight loads (9 mem-issues/8FMA -> 12/32)
//  - knorm: float4 nw loads per 4-ci chunk
// Shapes: B=4, C=64, D=128, L=4096 (l = h*256 + w*16 + t), N=16, R=8.
// ---------------------------------------------------------------------------

#define NL 4096

typedef unsigned short u16;
typedef unsigned int u32;

__device__ __forceinline__ float siluf_(float x) { return x / (1.f + __expf(-x)); }
__device__ __forceinline__ float softplusf_(float x) {
  return (x > 20.f) ? x : log1pf(__expf(x));
}
__device__ __forceinline__ u16 f2bf(float f) {
  u32 u = __float_as_uint(f);
  u += 0x7fffu + ((u >> 16) & 1u);
  return (u16)(u >> 16);
}
__device__ __forceinline__ float bflo(u32 v) { return __uint_as_float(v << 16); }
__device__ __forceinline__ float bfhi(u32 v) { return __uint_as_float(v & 0xFFFF0000u); }

// Sum over the 16-lane DPP row via rotations 1,2,4,8 (VALU pipe, no DS).
__device__ __forceinline__ float rowsum16_(float p) {
  int q;
  q = __builtin_amdgcn_mov_dpp(__float_as_int(p), 0x121, 0xf, 0xf, false);
  p += __int_as_float(q);
  q = __builtin_amdgcn_mov_dpp(__float_as_int(p), 0x122, 0xf, 0xf, false);
  p += __int_as_float(q);
  q = __builtin_amdgcn_mov_dpp(__float_as_int(p), 0x124, 0xf, 0xf, false);
  p += __int_as_float(q);
  q = __builtin_amdgcn_mov_dpp(__float_as_int(p), 0x128, 0xf, 0xf, false);
  p += __int_as_float(q);
  return p;
}

// Per-b slab offsets (fp32 elements; bf16 regions use u16 views at same base)
#define OXZ  0u          // xz [256][4096] fp32; becomes conv3 partials q0/q1
#define OUCF 1048576u    // ucf [128][4096] bf16 (u16 view)
#define OUCB 1572864u    // ucb [128][4096] bf16 (flipped coords)
#define ODLF 2424832u    // dlf [128][4096] bf16
#define ODLB 2949120u    // dlb [128][4096] bf16 (flipped coords)
#define OYF  3473408u    // yf [128][4096] fp32; becomes conv3 partial q2 (OX4B)
#define OYB  3997696u    // yb [128][4096] fp32 (flipped coords)
#define OO   4521984u    // scan scratch: P [262144] S [262144] fp32
#define OO2  5046272u    // bct [2][4096][32] bf16 until kscanC; then o2 [4096][64] fp32
#define OX4  5308416u    // conv3 partial q3 (+bias+residual)
#define OX4B 3473408u    // conv3 partial q2 (over dead yf)
#define PER_B 5570560u

#define NCH 64   // scan chunks
#define CL  64   // chunk length

// 1. xz[e,l] = sum_c in_proj_w[e,c] * seq[c,l].
__global__ __launch_bounds__(256) void kxz(
    const float* __restrict__ x, const float* __restrict__ wip,
    float* __restrict__ ws, int b0) {
  int bi = blockIdx.y, gb = b0 + bi;
  float* s = ws + (size_t)bi * PER_B;
  int bid = blockIdx.x;
  int h = bid >> 4, w = bid & 15;
  int tid = threadIdx.x;
  __shared__ float xs[64][16];
  for (int i = tid; i < 1024; i += 256) {
    int c = i >> 4, t = i & 15;
    xs[c][t] = x[(size_t)(gb * 64 + c) * NL + t * 256 + h * 16 + w];
  }
  __syncthreads();
  int e = tid;
  float acc[16];
#pragma unroll
  for (int t = 0; t < 16; ++t) acc[t] = 0.f;
  for (int c = 0; c < 64; ++c) {
    float wv = wip[e * 64 + c];
#pragma unroll
    for (int t = 0; t < 16; ++t) acc[t] = fmaf(wv, xs[c][t], acc[t]);
  }
  float4* dst = (float4*)(s + OXZ + (size_t)e * NL + h * 256 + w * 16);
#pragma unroll
  for (int q = 0; q < 4; ++q)
    dst[q] = make_float4(acc[q * 4], acc[q * 4 + 1], acc[q * 4 + 2], acc[q * 4 + 3]);
}

// 2. Fused prep per (bi, 32-l tile): dwconv+silu, x_dbl (float4), delta, bct.
__global__ __launch_bounds__(256) void k2prep(
    const float* __restrict__ cwf, const float* __restrict__ cbf,
    const float* __restrict__ xpf, const float* __restrict__ dtwf,
    const float* __restrict__ dtbf,
    const float* __restrict__ cwb, const float* __restrict__ cbb,
    const float* __restrict__ xpb, const float* __restrict__ dtwb,
    const float* __restrict__ dtbb,
    float* __restrict__ ws) {
  int bi = blockIdx.y;
  float* s = ws + (size_t)bi * PER_B;
  int lt = blockIdx.x;
  int l0 = lt * 32;
  int l0b = (127 - lt) * 32;
  int tid = threadIdx.x;

  __shared__ float pool[128 * 40];   // X[128][40] during dwconv; xds after
  __shared__ float ucs[2][128][32];
  float (*X)[40] = (float(*)[40])pool;

  for (int i = tid; i < 128 * 38; i += 256) {
    int d = i / 38, j = i - d * 38;
    int l = l0 - 3 + j;
    X[d][j] = (l >= 0 && l < NL) ? s[OXZ + (size_t)d * NL + l] : 0.f;
  }
  __syncthreads();

  u16* ucfp = (u16*)(s + OUCF);
  u16* ucbp = (u16*)(s + OUCB);
  for (int i = tid; i < 2 * 128 * 32; i += 256) {
    int br = i >> 12, rem = i & 4095;
    int d = rem >> 5, li = rem & 31;
    float a;
    if (br == 0) {
      a = cbf[d];
#pragma unroll
      for (int k = 0; k < 4; ++k) a = fmaf(cwf[d * 4 + k], X[d][li + k], a);
    } else {
      a = cbb[d];
#pragma unroll
      for (int k = 0; k < 4; ++k) a = fmaf(cwb[d * 4 + k], X[d][37 - li - k], a);
    }
    a = siluf_(a);
    ucs[br][d][li] = a;
    int lg = br ? (l0b + li) : (l0 + li);
    (br ? ucbp : ucfp)[(size_t)d * NL + lg] = f2bf(a);
  }
  __syncthreads();  // X dead; pool becomes xds [2][40][33]

  float* xds = pool;
  for (int i = tid; i < 640; i += 256) {
    int br = i / 320;
    int rem = i - br * 320;
    int e = rem >> 3, liq = rem & 7;
    const float* xp = br ? xpb : xpf;
    float4 acc = make_float4(0.f, 0.f, 0.f, 0.f);
    for (int d = 0; d < 128; ++d) {
      float wv = xp[e * 128 + d];
      const float4 u4 = *(const float4*)&ucs[br][d][liq * 4];
      acc.x = fmaf(wv, u4.x, acc.x);
      acc.y = fmaf(wv, u4.y, acc.y);
      acc.z = fmaf(wv, u4.z, acc.z);
      acc.w = fmaf(wv, u4.w, acc.w);
    }
    float* dst = &xds[(br * 40 + e) * 33 + liq * 4];
    dst[0] = acc.x; dst[1] = acc.y; dst[2] = acc.z; dst[3] = acc.w;
  }
  __syncthreads();

  u16* dlfp = (u16*)(s + ODLF);
  u16* dlbp = (u16*)(s + ODLB);
  for (int i = tid; i < 2 * 128 * 32; i += 256) {
    int br = i >> 12, rem = i & 4095;
    int d = rem >> 5, li = rem & 31;
    const float* dtw = br ? dtwb : dtwf;
    float pre = (br ? dtbb : dtbf)[d];
#pragma unroll
    for (int r = 0; r < 8; ++r)
      pre = fmaf(dtw[d * 8 + r], xds[(br * 40 + r) * 33 + li], pre);
    int lg = br ? (l0b + li) : (l0 + li);
    (br ? dlbp : dlfp)[(size_t)d * NL + lg] = f2bf(softplusf_(pre));
  }
  u16* bctp = (u16*)(s + OO2);
  for (int i = tid; i < 2 * 32 * 32; i += 256) {
    int dir = i >> 10;
    int li = (i >> 5) & 31, k = i & 31;
    int lg = dir ? (l0b + li) : (l0 + li);
    bctp[((size_t)dir * 4096 + lg) * 32 + k] = f2bf(xds[(dir * 40 + 8 + k) * 33 + li]);
  }
}

// 5a. Phase A: 16 d-rows/block; chunk bct (bf16) staged to fp32 LDS;
// ushort8 dl/uc loads = 8 steps per load pair.
__global__ __launch_bounds__(256) void kscanA(
    const float* __restrict__ Alf, const float* __restrict__ Alb,
    float* __restrict__ ws) {
  int bi = blockIdx.y;
  float* s = ws + (size_t)bi * PER_B;
  int xid = blockIdx.x;
  int chunk = xid >> 4, dir = (xid >> 3) & 1, d8 = xid & 7;
  int tid = threadIdx.x;
  int wv = tid >> 6, lane = tid & 63;
  int n = lane & 15, g = lane >> 4;
  int d = d8 * 16 + wv * 4 + g;
  int l0 = chunk * CL;
  __shared__ float bl[CL * 32];
  {
    const u16* bctp = (const u16*)(s + OO2) + ((size_t)dir * 4096 + l0) * 32;
    for (int i = tid; i < CL * 32; i += 256)
      bl[i] = __uint_as_float(((u32)bctp[i]) << 16);
  }
  __syncthreads();
  const u16* ucp = (const u16*)(s + (dir ? OUCB : OUCF)) + (size_t)d * NL + l0;
  const u16* dlp = (const u16*)(s + (dir ? ODLB : ODLF)) + (size_t)d * NL + l0;
  float A = -__expf((dir ? Alb : Alf)[d * 16 + n]);
  float P = 1.f, S = 0.f;
  for (int i0 = 0; i0 < CL; i0 += 8) {
    uint4 dq = *(const uint4*)(dlp + i0);
    uint4 uq = *(const uint4*)(ucp + i0);
    float dv[8] = {bflo(dq.x), bfhi(dq.x), bflo(dq.y), bfhi(dq.y),
                   bflo(dq.z), bfhi(dq.z), bflo(dq.w), bfhi(dq.w)};
    float uv[8] = {bflo(uq.x), bfhi(uq.x), bflo(uq.y), bfhi(uq.y),
                   bflo(uq.z), bfhi(uq.z), bflo(uq.w), bfhi(uq.w)};
#pragma unroll
    for (int j = 0; j < 8; ++j) {
      float dA = __expf(dv[j] * A);
      S = fmaf(dA, S, dv[j] * bl[(i0 + j) * 32 + n] * uv[j]);
      P *= dA;
    }
  }
  size_t cidx = ((size_t)(chunk * 2 + dir) * 128 + d) * 16 + n;
  s[OO + cidx] = P;
  s[OO + 262144u + cidx] = S;
}

// 5b. Phase B: carry combine.
__global__ __launch_bounds__(64) void kscanB(float* __restrict__ ws) {
  int bi = blockIdx.y;
  float* s = ws + (size_t)bi * PER_B;
  int dir = blockIdx.x >> 5, dblk = blockIdx.x & 31;
  int tid = threadIdx.x;
  size_t base = (size_t)dir * 2048 + dblk * 64 + tid;
  float carry = 0.f;
#pragma unroll 4
  for (int c = 0; c < NCH; ++c) {
    size_t idx = (size_t)c * 4096 + base;
    float pv = s[OO + idx], sv = s[OO + 262144u + idx];
    s[OO + 262144u + idx] = carry;
    carry = fmaf(pv, carry, sv);
  }
}

// 5c. Phase C: seeded re-scan; bf16 inputs; DPP row-sum; ps[16][65] staging.
__global__ __launch_bounds__(256) void kscanC(
    const float* __restrict__ Alf, const float* __restrict__ Df,
    const float* __restrict__ Alb, const float* __restrict__ Db,
    float* __restrict__ ws) {
  int bi = blockIdx.y;
  float* s = ws + (size_t)bi * PER_B;
  int xid = blockIdx.x;
  int chunk = xid >> 4, dir = (xid >> 3) & 1, d8 = xid & 7;
  int tid = threadIdx.x;
  int wv = tid >> 6, lane = tid & 63;
  int n = lane & 15, g = lane >> 4;
  int d = d8 * 16 + wv * 4 + g;
  int l0 = chunk * CL;
  __shared__ float bl[CL * 32];
  __shared__ float ps[16][65];
  {
    const u16* bctp = (const u16*)(s + OO2) + ((size_t)dir * 4096 + l0) * 32;
    for (int i = tid; i < CL * 32; i += 256)
      bl[i] = __uint_as_float(((u32)bctp[i]) << 16);
  }
  __syncthreads();
  const u16* ucp = (const u16*)(s + (dir ? OUCB : OUCF)) + (size_t)d * NL + l0;
  const u16* dlp = (const u16*)(s + (dir ? ODLB : ODLF)) + (size_t)d * NL + l0;
  float* ybase = s + (dir ? OYB : OYF);
  float A = -__expf((dir ? Alb : Alf)[d * 16 + n]);
  float Dv = (dir ? Db : Df)[d];
  size_t cidx = ((size_t)(chunk * 2 + dir) * 128 + d) * 16 + n;
  float h = s[OO + 262144u + cidx];
  int prow = wv * 4 + g;
  for (int i0 = 0; i0 < CL; i0 += 8) {
    uint4 dq = *(const uint4*)(dlp + i0);
    uint4 uq = *(const uint4*)(ucp + i0);
    float dv[8] = {bflo(dq.x), bfhi(dq.x), bflo(dq.y), bfhi(dq.y),
                   bflo(dq.z), bfhi(dq.z), bflo(dq.w), bfhi(dq.w)};
    float uv[8] = {bflo(uq.x), bfhi(uq.x), bflo(uq.y), bfhi(uq.y),
                   bflo(uq.z), bfhi(uq.z), bflo(uq.w), bfhi(uq.w)};
#pragma unroll
    for (int j = 0; j < 8; ++j) {
      int i = i0 + j;
      float dA = __expf(dv[j] * A);
      h = fmaf(dA, h, dv[j] * bl[i * 32 + n] * uv[j]);
      float p = rowsum16_(h * bl[i * 32 + 16 + n]);
      if (n == 0) ps[prow][i] = fmaf(uv[j], Dv, p);
    }
  }
  __syncthreads();
  for (int i = tid; i < 16 * CL; i += 256) {
    int row = i >> 6, col = i & 63;
    ybase[(size_t)(d8 * 16 + row) * NL + l0 + col] = ps[row][col];
  }
}

// 6. Fused gate + out-proj. Block = 32-l tile.
// Phase2 d-step-4 with float4 weight loads: 12 mem-issues per 32 FMA.
__global__ __launch_bounds__(256) void koutg(
    const float* __restrict__ wout, float* __restrict__ ws) {
  int bi = blockIdx.y;
  float* s = ws + (size_t)bi * PER_B;
  int lt = blockIdx.x;
  int l0 = lt * 32;
  int tid = threadIdx.x;
  __shared__ float ot[128][32];
  __shared__ float ot2[64][33];
  for (int i = tid; i < 128 * 32; i += 256) {
    int d = i >> 5, li = i & 31;
    int l = l0 + li;
    float z = s[OXZ + (size_t)(128 + d) * NL + l];
    float v = s[OYF + (size_t)d * NL + l] + s[OYB + (size_t)d * NL + (NL - 1 - l)];
    ot[d][li] = v * siluf_(z);
  }
  __syncthreads();
  {
    int li = tid & 31, cg = tid >> 5;
    float acc[8];
#pragma unroll
    for (int j = 0; j < 8; ++j) acc[j] = 0.f;
    for (int d4 = 0; d4 < 128; d4 += 4) {
      float o0 = ot[d4][li], o1 = ot[d4 + 1][li];
      float o2v = ot[d4 + 2][li], o3 = ot[d4 + 3][li];
#pragma unroll
      for (int j = 0; j < 8; ++j) {
        float4 w4 = *(const float4*)&wout[(cg * 8 + j) * 128 + d4];
        acc[j] = fmaf(w4.x, o0, fmaf(w4.y, o1, fmaf(w4.z, o2v, fmaf(w4.w, o3, acc[j]))));
      }
    }
#pragma unroll
    for (int j = 0; j < 8; ++j) ot2[cg * 8 + j][li] = acc[j];
  }
  __syncthreads();
  for (int i = tid; i < 32 * 64; i += 256) {
    int li = i >> 6, c = i & 63;
    s[OO2 + (size_t)(l0 + li) * 64 + c] = ot2[c][li];
  }
}

// 7. conv3d partials (R18 form). Grid = (t, hq, ciq<4): 256 blocks/slab.
__global__ __launch_bounds__(256) void kconv3(
    const float* __restrict__ pw, const float* __restrict__ pb,
    const float* __restrict__ xin, float* __restrict__ ws, int b0) {
  int bi = blockIdx.y, gb = b0 + bi;
  float* s = ws + (size_t)bi * PER_B;
  int t = blockIdx.x >> 4, hq = (blockIdx.x >> 2) & 3, ciq = blockIdx.x & 3;
  int h0 = hq * 4;
  int tid = threadIdx.x;
  int co = tid >> 2, hh = tid & 3;
  int h = h0 + hh;
  const float* xr = s + OO2;
  __shared__ float Xs[16][3][6][20];
  float acc[16];
#pragma unroll
  for (int w = 0; w < 16; ++w) acc[w] = 0.f;

  for (int i = tid; i < 16 * 360; i += 256) {
    int ci = i / 360;
    int rem = i - ci * 360;
    int tt = rem / 120;
    int rem2 = rem - tt * 120;
    int hh2 = rem2 / 20;
    int ww = rem2 - hh2 * 20;
    int ts = t + tt - 1, hs = h0 + hh2 - 1, wvv = ww - 1;
    float v = 0.f;
    if (ts >= 0 && ts < 16 && hs >= 0 && hs < 16 && wvv >= 0 && wvv < 16)
      v = xr[(size_t)(ciq * 16 + ci) * NL + ts * 256 + hs * 16 + wvv];
    Xs[ci][tt][hh2][ww] = v;
  }
  __syncthreads();
  const float* wc = pw + (co * 64 + ciq * 16) * 27;
  for (int ci = 0; ci < 16; ++ci) {
#pragma unroll
    for (int kt = 0; kt < 3; ++kt) {
#pragma unroll
      for (int kh = 0; kh < 3; ++kh) {
        const float* wr = wc + ci * 27 + kt * 9 + kh * 3;
        float wv0 = wr[0], wv1 = wr[1], wv2 = wr[2];
        const float* row = &Xs[ci][kt][hh + kh][0];
        float4 r0 = *(const float4*)&row[0];
        float4 r1 = *(const float4*)&row[4];
        float4 r2 = *(const float4*)&row[8];
        float4 r3 = *(const float4*)&row[12];
        float2 r4 = *(const float2*)&row[16];
        float xv[18] = {r0.x, r0.y, r0.z, r0.w, r1.x, r1.y, r1.z, r1.w,
                        r2.x, r2.y, r2.z, r2.w, r3.x, r3.y, r3.z, r3.w,
                        r4.x, r4.y};
#pragma unroll
        for (int w = 0; w < 16; ++w)
          acc[w] = fmaf(wv0, xv[w], fmaf(wv1, xv[w + 1], fmaf(wv2, xv[w + 2], acc[w])));
      }
    }
  }
  size_t off = (size_t)co * NL + t * 256 + h * 16;
  if (ciq == 3) {
    float bias = pb[co];
    size_t ibase = (size_t)(gb * 64 + co) * NL + t * 256 + h * 16;
#pragma unroll
    for (int w = 0; w < 16; ++w)
      s[OX4 + off + w] = acc[w] + bias + xin[ibase + w];
  } else {
    size_t dsto = (ciq == 2) ? OX4B : (ciq == 1 ? (OXZ + 262144u) : OXZ);
#pragma unroll
    for (int w = 0; w < 16; ++w)
      s[dsto + off + w] = acc[w];
  }
}

// 8. knorm: LDS-tiled 1x1x1 mix over the 4-partial sum + norm_b.
// Weight loads vectorized: one float4 of nw per 4-ci chunk (64 FMA).
__global__ __launch_bounds__(256) void knorm(
    const float* __restrict__ nw, const float* __restrict__ nb,
    float* __restrict__ out, float* __restrict__ ws, int b0) {
  int bi = blockIdx.y, gb = b0 + bi;
  float* s = ws + (size_t)bi * PER_B;
  int pt = blockIdx.x;
  int p0 = pt * 64;
  int tid = threadIdx.x;
  __shared__ float xs[64][64];
  for (int i = tid; i < 4096; i += 256) {
    int ci = i >> 6, p = i & 63;
    size_t o = (size_t)ci * NL + p0 + p;
    xs[ci][p] = s[OX4 + o] + s[OX4B + o] + s[OXZ + o] + s[OXZ + 262144u + o];
  }
  __syncthreads();
  int co = tid >> 2, pq = tid & 3;
  float acc[16];
#pragma unroll
  for (int j = 0; j < 16; ++j) acc[j] = 0.f;
  for (int ci = 0; ci < 64; ci += 4) {
    float4 w4 = *(const float4*)&nw[co * 64 + ci];
    float wv[4] = {w4.x, w4.y, w4.z, w4.w};
#pragma unroll
    for (int cc = 0; cc < 4; ++cc) {
      const float4* row = (const float4*)&xs[ci + cc][pq * 16];
      float4 a = row[0], b = row[1], c = row[2], e = row[3];
      acc[0] = fmaf(wv[cc], a.x, acc[0]);  acc[1] = fmaf(wv[cc], a.y, acc[1]);
      acc[2] = fmaf(wv[cc], a.z, acc[2]);  acc[3] = fmaf(wv[cc], a.w, acc[3]);
      acc[4] = fmaf(wv[cc], b.x, acc[4]);  acc[5] = fmaf(wv[cc], b.y, acc[5]);
      acc[6] = fmaf(wv[cc], b.z, acc[6]);  acc[7] = fmaf(wv[cc], b.w, acc[7]);
      acc[8] = fmaf(wv[cc], c.x, acc[8]);  acc[9] = fmaf(wv[cc], c.y, acc[9]);
      acc[10] = fmaf(wv[cc], c.z, acc[10]); acc[11] = fmaf(wv[cc], c.w, acc[11]);
      acc[12] = fmaf(wv[cc], e.x, acc[12]); acc[13] = fmaf(wv[cc], e.y, acc[13]);
      acc[14] = fmaf(wv[cc], e.z, acc[14]); acc[15] = fmaf(wv[cc], e.w, acc[15]);
    }
  }
  float bias = nb[co];
  float4* dst = (float4*)(out + (size_t)(gb * 64 + co) * NL + p0 + pq * 16);
#pragma unroll
  for (int q = 0; q < 4; ++q)
    dst[q] = make_float4(acc[q * 4] + bias, acc[q * 4 + 1] + bias,
                         acc[q * 4 + 2] + bias, acc[q * 4 + 3] + bias);
}

// ---------------------------------------------------------------------------
extern "C" void kernel_launch(void* const* d_in, const int* in_sizes, int n_in,
                              void* d_out, int out_size, void* d_ws, size_t ws_size,
                              hipStream_t stream) {
  const float* x    = (const float*)d_in[0];
  const float* wip  = (const float*)d_in[1];
  const float* cwf  = (const float*)d_in[2];
  const float* cbf  = (const float*)d_in[3];
  const float* xpf  = (const float*)d_in[4];
  const float* dtwf = (const float*)d_in[5];
  const float* dtbf = (const float*)d_in[6];
  const float* Alf  = (const float*)d_in[7];
  const float* Df   = (const float*)d_in[8];
  const float* cwb  = (const float*)d_in[9];
  const float* cbb  = (const float*)d_in[10];
  const float* xpb  = (const float*)d_in[11];
  const float* dtwb = (const float*)d_in[12];
  const float* dtbb = (const float*)d_in[13];
  const float* Alb  = (const float*)d_in[14];
  const float* Db   = (const float*)d_in[15];
  const float* wout = (const float*)d_in[16];
  const float* pw   = (const float*)d_in[17];
  const float* pb   = (const float*)d_in[18];
  const float* nw   = (const float*)d_in[19];
  const float* nb   = (const float*)d_in[20];

  const size_t PER_B_BYTES = (size_t)PER_B * 4;  // 22,282,240 per batch slab
  int bcnt;
  if (ws_size >= 4 * PER_B_BYTES) bcnt = 4;
  else if (ws_size >= PER_B_BYTES) bcnt = 1;
  else return;
  int passes = 4 / bcnt;

  float* ws = (float*)d_ws;
  for (int p = 0; p < passes; ++p) {
    int b0 = p * bcnt;
    kxz   <<<dim3(256, bcnt), 256, 0, stream>>>(x, wip, ws, b0);
    k2prep<<<dim3(128, bcnt), 256, 0, stream>>>(cwf, cbf, xpf, dtwf, dtbf,
                                                cwb, cbb, xpb, dtwb, dtbb, ws);
    kscanA<<<dim3(1024, bcnt), 256, 0, stream>>>(Alf, Alb, ws);
    kscanB<<<dim3(64, bcnt), 64, 0, stream>>>(ws);
    kscanC<<<dim3(1024, bcnt), 256, 0, stream>>>(Alf, Df, Alb, Db, ws);
    koutg <<<dim3(128, bcnt), 256, 0, stream>>>(wout, ws);
    kconv3<<<dim3(256, bcnt), 256, 0, stream>>>(pw, pb, x, ws, b0);
    knorm <<<dim3(64, bcnt), 256, 0, stream>>>(nw, nb, (float*)d_out, ws, b0);
  }
}